// Round 1
// baseline (6633.361 us; speedup 1.0000x reference)
//
#include <hip/hip_runtime.h>
#include <hip/hip_bf16.h>
#include <cstdint>
#include <cstddef>

#define B 64
#define N 196
#define T 32
#define TM1 31
#define VOCAB 32000
#define EMB 256
#define HDIM 512
#define VDIM 256
#define ATT 256
#define G4 2048

__device__ __forceinline__ float fast_tanh(float x){
  x = fminf(fmaxf(x, -15.f), 15.f);
  float e = __expf(2.f*x);
  return (e - 1.f) / (e + 1.f);
}
__device__ __forceinline__ float fast_sig(float x){
  x = fminf(fmaxf(x, -30.f), 30.f);
  return 1.f / (1.f + __expf(-x));
}

// feat_mean -> h0, c0.  grid: B blocks x 256 threads
__global__ void k_init(const float* __restrict__ V, const float* __restrict__ Wh,
                       const float* __restrict__ bh, const float* __restrict__ Wc,
                       const float* __restrict__ bc, float* __restrict__ h0,
                       float* __restrict__ c0){
  int b = blockIdx.x, tid = threadIdx.x;
  __shared__ float fm[VDIM];
  const float* vb = V + (size_t)b*N*VDIM;
  float s = 0.f;
  for (int n=0;n<N;n++) s += vb[n*VDIM + tid];
  fm[tid] = s * (1.f/196.f);
  __syncthreads();
  for (int j=tid; j<HDIM; j+=256){
    float sh = bh[j], sc = bc[j];
    #pragma unroll 4
    for (int k=0;k<VDIM;k++){
      float f = fm[k];
      sh = fmaf(f, Wh[k*HDIM + j], sh);
      sc = fmaf(f, Wc[k*HDIM + j], sc);
    }
    h0[b*HDIM + j] = fast_tanh(sh);
    c0[b*HDIM + j] = fast_tanh(sc);
  }
}

// Uv = V @ U_att  (12544 x 256, K=256).  grid: 1568 blocks, 8 rows/block
__global__ void k_uv(const float* __restrict__ V, const float* __restrict__ U,
                     float* __restrict__ Uv){
  int tid = threadIdx.x;
  size_t r0 = (size_t)blockIdx.x * 8;
  __shared__ float vs[8][VDIM];
  for (int i=tid; i<8*VDIM; i+=256)
    vs[i>>8][i&255] = V[r0*VDIM + i];
  __syncthreads();
  float acc[8] = {0,0,0,0,0,0,0,0};
  int a = tid;
  #pragma unroll 4
  for (int k=0;k<VDIM;k++){
    float u = U[k*ATT + a];
    #pragma unroll
    for (int r=0;r<8;r++) acc[r] = fmaf(vs[r][k], u, acc[r]);
  }
  for (int r=0;r<8;r++) Uv[(r0 + r)*ATT + a] = acc[r];
}

// attention for one step: q = h@W_att; e = tanh(q+Uv)@v_att; softmax; ctx = a@V
// grid: B blocks x 256 threads
__global__ void k_att(const float* __restrict__ V, const float* __restrict__ Uv,
                      const float* __restrict__ Wa, const float* __restrict__ va,
                      const float* __restrict__ hin, float* __restrict__ ctx){
  int b = blockIdx.x, tid = threadIdx.x;
  __shared__ float hs[HDIM];
  __shared__ float qs[ATT];
  __shared__ float vat[ATT];
  __shared__ float es[N];
  __shared__ float red[16];
  for (int i=tid;i<HDIM;i+=256) hs[i] = hin[b*HDIM+i];
  vat[tid] = va[tid];
  __syncthreads();
  {
    float s = 0.f;
    #pragma unroll 4
    for (int k=0;k<HDIM;k++) s = fmaf(hs[k], Wa[k*ATT + tid], s);
    qs[tid] = s;
  }
  __syncthreads();
  int wv = tid >> 6, lane = tid & 63;
  for (int n=wv; n<N; n+=4){
    const float* uv = Uv + ((size_t)b*N + n)*ATT;
    float s = 0.f;
    #pragma unroll
    for (int a0=0; a0<ATT; a0+=64){
      int a = a0 + lane;
      float x = qs[a] + uv[a];
      s = fmaf(vat[a], fast_tanh(x), s);
    }
    #pragma unroll
    for (int off=32; off>0; off>>=1) s += __shfl_down(s, off, 64);
    if (lane==0) es[n] = s;
  }
  __syncthreads();
  float v = (tid < N) ? es[tid] : -3e38f;
  float m = v;
  #pragma unroll
  for (int off=32; off>0; off>>=1) m = fmaxf(m, __shfl_down(m, off, 64));
  if (lane==0) red[wv] = m;
  __syncthreads();
  if (tid==0) red[8] = fmaxf(fmaxf(red[0],red[1]), fmaxf(red[2],red[3]));
  __syncthreads();
  float p = (tid < N) ? __expf(v - red[8]) : 0.f;
  float s2 = p;
  #pragma unroll
  for (int off=32; off>0; off>>=1) s2 += __shfl_down(s2, off, 64);
  if (lane==0) red[4+wv] = s2;
  __syncthreads();
  if (tid==0) red[9] = red[4]+red[5]+red[6]+red[7];
  __syncthreads();
  float inv = 1.f / red[9];
  if (tid < N) es[tid] = p * inv;
  __syncthreads();
  {
    const float* vb = V + (size_t)b*N*VDIM;
    float s = 0.f;
    for (int n=0;n<N;n++) s = fmaf(es[n], vb[n*VDIM + tid], s);
    ctx[b*VDIM + tid] = s;
  }
}

// gates + LSTM update for one step.
// grid: 256 blocks = 8 batch-slices (8 b) x 32 j-slices (16 j).
__global__ __launch_bounds__(256)
void k_gates(const float* __restrict__ embed, const int* __restrict__ y, int t,
             const float* __restrict__ ctx, const float* __restrict__ hin,
             float* __restrict__ c_state, float* __restrict__ hout,
             float* __restrict__ Hall,
             const float* __restrict__ Wih, const float* __restrict__ Whh,
             const float* __restrict__ bih, const float* __restrict__ bhh){
  int tid = threadIdx.x;
  int bs = blockIdx.x >> 5, js = blockIdx.x & 31;
  int b0 = bs*8, j0 = js*16;
  __shared__ float zs[8][1024];   // [x(256) | ctx(256) | h(512)] per batch
  __shared__ float gs[8][16][4];
  for (int i=tid; i<8192; i+=256){
    int bb = i >> 10, k = i & 1023;
    int b = b0 + bb;
    float val;
    if (k < 256)      val = embed[(size_t)y[b*T + t]*EMB + k];
    else if (k < 512) val = ctx[b*VDIM + (k-256)];
    else              val = hin[b*HDIM + (k-512)];
    zs[bb][k] = val;
  }
  __syncthreads();
  int jl = tid & 15, bb = (tid>>4)&7, gp = tid>>7;
  int col0 = (gp*2)*HDIM + j0 + jl;
  int col1 = (gp*2+1)*HDIM + j0 + jl;
  float a0 = bih[col0] + bhh[col0];
  float a1 = bih[col1] + bhh[col1];
  const float* w0 = Wih + col0;
  const float* w1 = Wih + col1;
  const float* zrow = zs[bb];
  #pragma unroll 4
  for (int k=0;k<512;k++){
    float zv = zrow[k];
    a0 = fmaf(zv, w0[(size_t)k*G4], a0);
    a1 = fmaf(zv, w1[(size_t)k*G4], a1);
  }
  const float* v0 = Whh + col0;
  const float* v1 = Whh + col1;
  #pragma unroll 4
  for (int k=0;k<512;k++){
    float hv = zrow[512+k];
    a0 = fmaf(hv, v0[(size_t)k*G4], a0);
    a1 = fmaf(hv, v1[(size_t)k*G4], a1);
  }
  gs[bb][jl][gp*2]   = a0;
  gs[bb][jl][gp*2+1] = a1;
  __syncthreads();
  if (tid < 128){
    int bb2 = tid >> 4, jl2 = tid & 15;
    int b = b0 + bb2, j = j0 + jl2;
    float ig = fast_sig(gs[bb2][jl2][0]);
    float fg = fast_sig(gs[bb2][jl2][1]);
    float gg = fast_tanh(gs[bb2][jl2][2]);
    float og = fast_sig(gs[bb2][jl2][3]);
    float c = c_state[b*HDIM + j];
    c = fmaf(fg, c, ig*gg);
    float h = og * fast_tanh(c);
    c_state[b*HDIM + j] = c;
    hout[b*HDIM + j] = h;
    Hall[((size_t)t*B + b)*HDIM + j] = h;
  }
}

// P = H @ W_proj  (1984 x 256, K=512).  grid: 248 blocks, 8 rows/block
__global__ void k_proj(const float* __restrict__ H, const float* __restrict__ Wp,
                       float* __restrict__ P){
  int tid = threadIdx.x;
  size_t r0 = (size_t)blockIdx.x * 8;
  __shared__ float hs[8][HDIM];
  for (int i=tid; i<8*HDIM; i+=256)
    hs[i>>9][i&511] = H[r0*HDIM + i];
  __syncthreads();
  float acc[8] = {0,0,0,0,0,0,0,0};
  int e = tid;
  #pragma unroll 4
  for (int k=0;k<HDIM;k++){
    float w = Wp[k*EMB + e];
    #pragma unroll
    for (int r=0;r<8;r++) acc[r] = fmaf(hs[r][k], w, acc[r]);
  }
  for (int r=0;r<8;r++) P[(r0 + r)*EMB + e] = acc[r];
}

// logits = P @ embed^T  (1984 x 32000, K=256). 128x128 tile, 8x8 per thread.
__global__ __launch_bounds__(256)
void k_logits(const float* __restrict__ P, const float* __restrict__ E,
              float* __restrict__ out){
  __shared__ float Pl[32][129];
  __shared__ float El[32][129];
  int tid = threadIdx.x;
  int tx = tid & 15, ty = tid >> 4;
  int c0 = blockIdx.x * 128, r0 = blockIdx.y * 128;
  float acc[8][8];
  #pragma unroll
  for (int i=0;i<8;i++)
    #pragma unroll
    for (int j=0;j<8;j++) acc[i][j]=0.f;
  int kk = tid & 31, rb = tid >> 5;   // rb in 0..7
  for (int kc=0; kc<EMB; kc+=32){
    #pragma unroll
    for (int i=0;i<16;i++){
      int pr = r0 + rb + i*8; if (pr > TM1*B-1) pr = TM1*B-1;
      Pl[kk][rb + i*8] = P[(size_t)pr*EMB + kc + kk];
      int er = c0 + rb + i*8;
      El[kk][rb + i*8] = E[(size_t)er*EMB + kc + kk];
    }
    __syncthreads();
    for (int k=0;k<32;k++){
      float pr_[8], ec[8];
      #pragma unroll
      for (int i=0;i<8;i++) pr_[i] = Pl[k][ty*8+i];
      #pragma unroll
      for (int j=0;j<8;j++) ec[j] = El[k][tx*8+j];
      #pragma unroll
      for (int i=0;i<8;i++)
        #pragma unroll
        for (int j=0;j<8;j++) acc[i][j] = fmaf(pr_[i], ec[j], acc[i][j]);
    }
    __syncthreads();
  }
  #pragma unroll
  for (int i=0;i<8;i++){
    int row = r0 + ty*8 + i;
    if (row < TM1*B){
      int t = row >> 6, b = row & 63;
      float* orow = out + ((size_t)(b*TM1 + t))*VOCAB + c0 + tx*8;
      #pragma unroll
      for (int j=0;j<8;j++) orow[j] = acc[i][j];
    }
  }
}

extern "C" void kernel_launch(void* const* d_in, const int* in_sizes, int n_in,
                              void* d_out, int out_size, void* d_ws, size_t ws_size,
                              hipStream_t stream){
  const float* V      = (const float*)d_in[0];
  const int*   y      = (const int*)  d_in[1];
  const float* embed  = (const float*)d_in[2];
  const float* W_att  = (const float*)d_in[3];
  const float* U_att  = (const float*)d_in[4];
  const float* v_att  = (const float*)d_in[5];
  const float* W_ih   = (const float*)d_in[6];
  const float* W_hh   = (const float*)d_in[7];
  const float* b_ih   = (const float*)d_in[8];
  const float* b_hh   = (const float*)d_in[9];
  const float* W_inith= (const float*)d_in[10];
  const float* b_inith= (const float*)d_in[11];
  const float* W_initc= (const float*)d_in[12];
  const float* b_initc= (const float*)d_in[13];
  const float* W_proj = (const float*)d_in[14];
  float* out = (float*)d_out;

  float* ws    = (float*)d_ws;
  float* Uv    = ws;                               // B*N*ATT   = 3,211,264 f
  float* hbuf0 = Uv    + (size_t)B*N*ATT;          // B*HDIM
  float* hbuf1 = hbuf0 + B*HDIM;
  float* c_st  = hbuf1 + B*HDIM;
  float* ctx   = c_st  + B*HDIM;                   // B*VDIM
  float* Hall  = ctx   + B*VDIM;                   // TM1*B*HDIM = 1,015,808 f
  float* P     = Hall  + (size_t)TM1*B*HDIM;       // TM1*B*EMB  = 507,904 f

  k_init<<<B, 256, 0, stream>>>(V, W_inith, b_inith, W_initc, b_initc, hbuf0, c_st);
  k_uv<<<(B*N)/8, 256, 0, stream>>>(V, U_att, Uv);

  float* hb[2] = {hbuf0, hbuf1};
  for (int t=0;t<TM1;t++){
    const float* hin = hb[t&1];
    float* hout = hb[(t+1)&1];
    k_att<<<B, 256, 0, stream>>>(V, Uv, W_att, v_att, hin, ctx);
    k_gates<<<256, 256, 0, stream>>>(embed, y, t, ctx, hin, c_st, hout, Hall,
                                     W_ih, W_hh, b_ih, b_hh);
  }
  k_proj<<<(TM1*B)/8, 256, 0, stream>>>(Hall, W_proj, P);
  dim3 g(VOCAB/128, (TM1*B + 127)/128);
  k_logits<<<g, 256, 0, stream>>>(P, embed, out);
}

// Round 2
// 3281.504 us; speedup vs baseline: 2.0214x; 2.0214x over previous
//
#include <hip/hip_runtime.h>
#include <hip/hip_bf16.h>
#include <cstdint>
#include <cstddef>

#define B 64
#define N 196
#define T 32
#define TM1 31
#define VOCAB 32000
#define EMB 256
#define HDIM 512
#define VDIM 256
#define ATT 256
#define G4 2048

__device__ __forceinline__ float fast_tanh(float x){
  x = fminf(fmaxf(x, -15.f), 15.f);
  float e = __expf(2.f*x);
  return (e - 1.f) / (e + 1.f);
}
__device__ __forceinline__ float fast_sig(float x){
  x = fminf(fmaxf(x, -30.f), 30.f);
  return 1.f / (1.f + __expf(-x));
}

// feat_mean -> h0, c0.  grid: B blocks x 256 threads
__global__ void k_init(const float* __restrict__ V, const float* __restrict__ Wh,
                       const float* __restrict__ bh, const float* __restrict__ Wc,
                       const float* __restrict__ bc, float* __restrict__ h0,
                       float* __restrict__ c0){
  int b = blockIdx.x, tid = threadIdx.x;
  __shared__ float fm[VDIM];
  const float* vb = V + (size_t)b*N*VDIM;
  float s = 0.f;
  for (int n=0;n<N;n++) s += vb[n*VDIM + tid];
  fm[tid] = s * (1.f/196.f);
  __syncthreads();
  for (int j=tid; j<HDIM; j+=256){
    float sh = bh[j], sc = bc[j];
    #pragma unroll 4
    for (int k=0;k<VDIM;k++){
      float f = fm[k];
      sh = fmaf(f, Wh[k*HDIM + j], sh);
      sc = fmaf(f, Wc[k*HDIM + j], sc);
    }
    h0[b*HDIM + j] = fast_tanh(sh);
    c0[b*HDIM + j] = fast_tanh(sc);
  }
}

// Uv = V @ U_att  (12544 x 256, K=256).  grid: 1568 blocks, 8 rows/block
__global__ void k_uv(const float* __restrict__ V, const float* __restrict__ U,
                     float* __restrict__ Uv){
  int tid = threadIdx.x;
  size_t r0 = (size_t)blockIdx.x * 8;
  __shared__ float vs[8][VDIM];
  for (int i=tid; i<8*VDIM; i+=256)
    vs[i>>8][i&255] = V[r0*VDIM + i];
  __syncthreads();
  float acc[8] = {0,0,0,0,0,0,0,0};
  int a = tid;
  #pragma unroll 4
  for (int k=0;k<VDIM;k++){
    float u = U[k*ATT + a];
    #pragma unroll
    for (int r=0;r<8;r++) acc[r] = fmaf(vs[r][k], u, acc[r]);
  }
  for (int r=0;r<8;r++) Uv[(r0 + r)*ATT + a] = acc[r];
}

// XWb[r][c] = sum_k embed[y]][k]*Wih[k][c] + bih[c] + bhh[c], r = t*64+b
// grid: (16 coltiles, 16 rowtiles) x 256
__global__ __launch_bounds__(256)
void k_xw(const float* __restrict__ embed, const int* __restrict__ y,
          const float* __restrict__ Wih, const float* __restrict__ bih,
          const float* __restrict__ bhh, float* __restrict__ XWb){
  __shared__ int ys[128];
  __shared__ float Xl[32][129];
  __shared__ float Wl[32][129];
  int tid = threadIdx.x;
  int c0 = blockIdx.x * 128, r0 = blockIdx.y * 128;
  if (tid < 128){
    int r = r0 + tid;
    ys[tid] = (r < TM1*B) ? y[(r & 63)*T + (r >> 6)] : 0;
  }
  int kk = tid & 31, rb = tid >> 5;          // X staging
  int wk = tid >> 7, wc = tid & 127;         // W staging
  int tx = tid & 15, ty = tid >> 4;
  float acc[8][8];
  #pragma unroll
  for (int i=0;i<8;i++)
    #pragma unroll
    for (int j=0;j<8;j++) acc[i][j]=0.f;
  for (int kc=0; kc<EMB; kc+=32){
    __syncthreads();
    #pragma unroll
    for (int i=0;i<16;i++){
      Xl[kk][rb + i*8] = embed[(size_t)ys[rb + i*8]*EMB + kc + kk];
      Wl[wk + i*2][wc] = Wih[(size_t)(kc + wk + i*2)*G4 + c0 + wc];
    }
    __syncthreads();
    for (int k=0;k<32;k++){
      float pr_[8], ec[8];
      #pragma unroll
      for (int i=0;i<8;i++) pr_[i] = Xl[k][ty + 16*i];
      #pragma unroll
      for (int j=0;j<8;j++) ec[j] = Wl[k][tx + 16*j];
      #pragma unroll
      for (int i=0;i<8;i++)
        #pragma unroll
        for (int j=0;j<8;j++) acc[i][j] = fmaf(pr_[i], ec[j], acc[i][j]);
    }
  }
  float bb[8];
  #pragma unroll
  for (int j=0;j<8;j++){
    int c = c0 + tx + 16*j;
    bb[j] = bih[c] + bhh[c];
  }
  #pragma unroll
  for (int i=0;i<8;i++){
    int row = r0 + ty + 16*i;
    if (row < TM1*B){
      float* orow = XWb + (size_t)row*G4 + c0;
      #pragma unroll
      for (int j=0;j<8;j++) orow[tx + 16*j] = acc[i][j] + bb[j];
    }
  }
}

// Fused LSTM-pointwise(prev step) + attention.  grid: B blocks x 512 threads
__global__ __launch_bounds__(512)
void k_att(const float* __restrict__ V, const float* __restrict__ Uv,
           const float* __restrict__ Wa, const float* __restrict__ va,
           const float* __restrict__ gprev,  // XWb slice of step t-1, or null
           const float* __restrict__ h0, float* __restrict__ c_st,
           float* __restrict__ hwr,          // Hall slice t-1 (null if t==0)
           float* __restrict__ ctx){
  int b = blockIdx.x, tid = threadIdx.x;
  __shared__ float hs[HDIM];
  __shared__ float qs[ATT];
  __shared__ float vat[ATT];
  __shared__ float es[200];
  __shared__ float qp[512];
  __shared__ float redm[8], reds[8];
  __shared__ float sM, sInv;

  if (tid < 256) vat[tid] = va[tid];
  if (gprev){
    const float* grow = gprev + (size_t)b*G4;
    float gi = grow[tid], gf = grow[512+tid], gg = grow[1024+tid], go = grow[1536+tid];
    float c = c_st[b*HDIM + tid];
    c = fmaf(fast_sig(gf), c, fast_sig(gi)*fast_tanh(gg));
    float h = fast_sig(go) * fast_tanh(c);
    c_st[b*HDIM + tid] = c;
    hs[tid] = h;
    hwr[b*HDIM + tid] = h;
  } else {
    hs[tid] = h0[b*HDIM + tid];
  }
  __syncthreads();

  // q = h @ W_att   (K-split by 2)
  {
    int col = tid & 255, half = tid >> 8;
    int k0 = half*256;
    float s = 0.f;
    #pragma unroll 4
    for (int k=0;k<256;k++) s = fmaf(hs[k0+k], Wa[(size_t)(k0+k)*ATT + col], s);
    qp[tid] = s;
  }
  __syncthreads();
  if (tid < 256) qs[tid] = qp[tid] + qp[tid+256];
  __syncthreads();

  // e[n] = v . tanh(q + Uv[b,n])
  int wv = tid >> 6, lane = tid & 63;
  for (int n=wv; n<N; n+=8){
    const float* uv = Uv + ((size_t)b*N + n)*ATT;
    float s = 0.f;
    #pragma unroll
    for (int a0=0; a0<ATT; a0+=64){
      int a = a0 + lane;
      s = fmaf(vat[a], fast_tanh(qs[a] + uv[a]), s);
    }
    #pragma unroll
    for (int off=32; off>0; off>>=1) s += __shfl_down(s, off, 64);
    if (lane==0) es[n] = s;
  }
  __syncthreads();

  // softmax over es[0..195]
  float v = (tid < N) ? es[tid] : -3.0e38f;
  float m = v;
  #pragma unroll
  for (int off=32; off>0; off>>=1) m = fmaxf(m, __shfl_down(m, off, 64));
  if (lane==0) redm[wv] = m;
  __syncthreads();
  if (tid==0){
    float mm = redm[0];
    #pragma unroll
    for (int i=1;i<8;i++) mm = fmaxf(mm, redm[i]);
    sM = mm;
  }
  __syncthreads();
  float p = (tid < N) ? __expf(v - sM) : 0.f;
  float s2 = p;
  #pragma unroll
  for (int off=32; off>0; off>>=1) s2 += __shfl_down(s2, off, 64);
  if (lane==0) reds[wv] = s2;
  __syncthreads();
  if (tid==0){
    float ss = 0.f;
    #pragma unroll
    for (int i=0;i<8;i++) ss += reds[i];
    sInv = 1.f/ss;
  }
  __syncthreads();
  if (tid < N) es[tid] = p * sInv;
  __syncthreads();

  // ctx = a @ V   (K-split by 2 over n)
  {
    int col = tid & 255, half = tid >> 8;
    int n0 = half*98;
    const float* vb = V + (size_t)b*N*VDIM;
    float s = 0.f;
    #pragma unroll 2
    for (int n=n0; n<n0+98; n++) s = fmaf(es[n], vb[(size_t)n*VDIM + col], s);
    qp[tid] = s;
  }
  __syncthreads();
  if (tid < 256) ctx[b*VDIM + tid] = qp[tid] + qp[tid+256];
}

// gates partial: XWb[t] += [ctx|h] @ [Wih[256:512]; Whh]
// grid: 192 blocks (= kc*32 + coltile) x 256 threads
__global__ __launch_bounds__(256)
void k_gates(const float* __restrict__ ctx, const float* __restrict__ hprev,
             const float* __restrict__ Wih, const float* __restrict__ Whh,
             float* __restrict__ gout){
  int tid = threadIdx.x;
  int ct = blockIdx.x & 31, kcid = blockIdx.x >> 5;
  int c0 = ct * 64;
  __shared__ float zs[64][128];
  for (int i=tid; i<8192; i+=256){
    int b = i >> 7, kk = i & 127;
    float val;
    if (kcid < 2) val = ctx[b*VDIM + kcid*128 + kk];
    else          val = hprev[b*HDIM + kcid*128 - 256 + kk];
    zs[b][kk] = val;
  }
  const float* wbase = (kcid < 2) ? (Wih + (size_t)(256 + kcid*128)*G4)
                                  : (Whh + (size_t)(kcid*128 - 256)*G4);
  __syncthreads();
  int cg = tid & 15, bg = tid >> 4;
  float acc[4][4];
  #pragma unroll
  for (int i=0;i<4;i++)
    #pragma unroll
    for (int j=0;j<4;j++) acc[i][j]=0.f;
  #pragma unroll 4
  for (int k=0;k<128;k++){
    float4 w = *(const float4*)(wbase + (size_t)k*G4 + c0 + cg*4);
    #pragma unroll
    for (int bi=0;bi<4;bi++){
      float zv = zs[bg*4+bi][k];
      acc[bi][0] = fmaf(zv, w.x, acc[bi][0]);
      acc[bi][1] = fmaf(zv, w.y, acc[bi][1]);
      acc[bi][2] = fmaf(zv, w.z, acc[bi][2]);
      acc[bi][3] = fmaf(zv, w.w, acc[bi][3]);
    }
  }
  #pragma unroll
  for (int bi=0;bi<4;bi++){
    int b = bg*4 + bi;
    float* gp = gout + (size_t)b*G4 + c0 + cg*4;
    #pragma unroll
    for (int ci=0;ci<4;ci++) atomicAdd(gp + ci, acc[bi][ci]);
  }
}

// final pointwise for t=30 -> Hall[30]
__global__ __launch_bounds__(512)
void k_tail(const float* __restrict__ gprev, const float* __restrict__ c_st,
            float* __restrict__ hwr){
  int b = blockIdx.x, tid = threadIdx.x;
  const float* grow = gprev + (size_t)b*G4;
  float gi = grow[tid], gf = grow[512+tid], gg = grow[1024+tid], go = grow[1536+tid];
  float c = c_st[b*HDIM + tid];
  c = fmaf(fast_sig(gf), c, fast_sig(gi)*fast_tanh(gg));
  hwr[b*HDIM + tid] = fast_sig(go) * fast_tanh(c);
}

// P = H @ W_proj  (1984 x 256, K=512).  grid: 248 blocks, 8 rows/block
__global__ void k_proj(const float* __restrict__ H, const float* __restrict__ Wp,
                       float* __restrict__ P){
  int tid = threadIdx.x;
  size_t r0 = (size_t)blockIdx.x * 8;
  __shared__ float hs[8][HDIM];
  for (int i=tid; i<8*HDIM; i+=256)
    hs[i>>9][i&511] = H[r0*HDIM + i];
  __syncthreads();
  float acc[8] = {0,0,0,0,0,0,0,0};
  int e = tid;
  #pragma unroll 4
  for (int k=0;k<HDIM;k++){
    float w = Wp[k*EMB + e];
    #pragma unroll
    for (int r=0;r<8;r++) acc[r] = fmaf(hs[r][k], w, acc[r]);
  }
  for (int r=0;r<8;r++) P[(r0 + r)*EMB + e] = acc[r];
}

// logits = P @ embed^T  (1984 x 32000, K=256). 128x128 tile, strided 8x8.
__global__ __launch_bounds__(256)
void k_logits(const float* __restrict__ P, const float* __restrict__ E,
              float* __restrict__ out){
  __shared__ float Pl[32][129];
  __shared__ float El[32][129];
  int tid = threadIdx.x;
  int tx = tid & 15, ty = tid >> 4;
  int c0 = blockIdx.x * 128, r0 = blockIdx.y * 128;
  float acc[8][8];
  #pragma unroll
  for (int i=0;i<8;i++)
    #pragma unroll
    for (int j=0;j<8;j++) acc[i][j]=0.f;
  int kk = tid & 31, rb = tid >> 5;
  for (int kc=0; kc<EMB; kc+=32){
    __syncthreads();
    #pragma unroll
    for (int i=0;i<16;i++){
      int pr = r0 + rb + i*8; if (pr > TM1*B-1) pr = TM1*B-1;
      Pl[kk][rb + i*8] = P[(size_t)pr*EMB + kc + kk];
      int er = c0 + rb + i*8;
      El[kk][rb + i*8] = E[(size_t)er*EMB + kc + kk];
    }
    __syncthreads();
    for (int k=0;k<32;k++){
      float pr_[8], ec[8];
      #pragma unroll
      for (int i=0;i<8;i++) pr_[i] = Pl[k][ty + 16*i];
      #pragma unroll
      for (int j=0;j<8;j++) ec[j] = El[k][tx + 16*j];
      #pragma unroll
      for (int i=0;i<8;i++)
        #pragma unroll
        for (int j=0;j<8;j++) acc[i][j] = fmaf(pr_[i], ec[j], acc[i][j]);
    }
  }
  #pragma unroll
  for (int i=0;i<8;i++){
    int row = r0 + ty + 16*i;
    if (row < TM1*B){
      int t = row >> 6, b = row & 63;
      float* orow = out + ((size_t)(b*TM1 + t))*VOCAB + c0;
      #pragma unroll
      for (int j=0;j<8;j++) orow[tx + 16*j] = acc[i][j];
    }
  }
}

extern "C" void kernel_launch(void* const* d_in, const int* in_sizes, int n_in,
                              void* d_out, int out_size, void* d_ws, size_t ws_size,
                              hipStream_t stream){
  const float* V      = (const float*)d_in[0];
  const int*   y      = (const int*)  d_in[1];
  const float* embed  = (const float*)d_in[2];
  const float* W_att  = (const float*)d_in[3];
  const float* U_att  = (const float*)d_in[4];
  const float* v_att  = (const float*)d_in[5];
  const float* W_ih   = (const float*)d_in[6];
  const float* W_hh   = (const float*)d_in[7];
  const float* b_ih   = (const float*)d_in[8];
  const float* b_hh   = (const float*)d_in[9];
  const float* W_inith= (const float*)d_in[10];
  const float* b_inith= (const float*)d_in[11];
  const float* W_initc= (const float*)d_in[12];
  const float* b_initc= (const float*)d_in[13];
  const float* W_proj = (const float*)d_in[14];
  float* out = (float*)d_out;

  float* ws   = (float*)d_ws;
  float* Uv   = ws;                                // 3,211,264 f
  float* h0   = Uv   + (size_t)B*N*ATT;            // 32768
  float* c_st = h0   + B*HDIM;                     // 32768
  float* ctx  = c_st + B*HDIM;                     // 16384
  float* Hall = ctx  + B*VDIM;                     // 1,015,808
  float* XWb  = Hall + (size_t)TM1*B*HDIM;         // 4,063,232
  float* P    = XWb  + (size_t)TM1*B*G4;           // 507,904

  k_init<<<B, 256, 0, stream>>>(V, W_inith, b_inith, W_initc, b_initc, h0, c_st);
  k_uv<<<(B*N)/8, 256, 0, stream>>>(V, U_att, Uv);
  k_xw<<<dim3(16,16), 256, 0, stream>>>(embed, y, W_ih, b_ih, b_hh, XWb);

  for (int t=0;t<TM1;t++){
    const float* gprev = (t==0) ? nullptr : (XWb + (size_t)(t-1)*B*G4);
    float* hwr = (t==0) ? nullptr : (Hall + (size_t)(t-1)*B*HDIM);
    const float* hprev = (t==0) ? h0 : (Hall + (size_t)(t-1)*B*HDIM);
    k_att<<<B, 512, 0, stream>>>(V, Uv, W_att, v_att, gprev, h0, c_st, hwr, ctx);
    k_gates<<<192, 256, 0, stream>>>(ctx, hprev, W_ih, W_hh, XWb + (size_t)t*B*G4);
  }
  k_tail<<<B, 512, 0, stream>>>(XWb + (size_t)30*B*G4, c_st, Hall + (size_t)30*B*HDIM);
  k_proj<<<(TM1*B)/8, 256, 0, stream>>>(Hall, W_proj, P);
  dim3 g(VOCAB/128, (TM1*B + 127)/128);
  k_logits<<<g, 256, 0, stream>>>(P, embed, out);
}